// Round 2
// baseline (152.887 us; speedup 1.0000x reference)
//
#include <hip/hip_runtime.h>

#define NB   1024
#define NL   4096
#define TPB  256
#define NCH  4                   // chunks of 4 steps -> 16 steps/thread

typedef float v2f __attribute__((ext_vector_type(2)));

__device__ __forceinline__ float fast_rcp(float x) { return __builtin_amdgcn_rcpf(x); }
__device__ __forceinline__ float fexp2(float x) { return __builtin_amdgcn_exp2f(x); }  // 2^x
__device__ __forceinline__ float flog2(float x) { return __builtin_amdgcn_logf(x); }   // log2(x)

#define L2E 1.44269504088896340736f
#define LN2 0.69314718055994530942f

// Even part of softplus in log2 domain: F(x) = log2(1+2^x) - x/2 = F(-x).
// Cubic in s=x^2; max |err| ~1e-3 on |x|<=4.
#define SP_C0 1.0f
#define SP_C1 0.0864667f
#define SP_C2 (-0.0015685f)
#define SP_C3 2.5763e-5f

// One block per row. Whole row (4096 steps x 5 floats = 80 KB) staged to LDS
// via global_load_lds width=16 (no VGPR round trip). XOR float4-swizzle
// (involution j ^ ((j>>3)&7)) applied on the GLOBAL source address with a
// linear LDS destination (global_load_lds writes base+lane*16 only), and the
// same XOR applied on the LDS read side -> logical element i lives at
// tile[sw(i)], strided 20-float4 per-thread reads are bank-conflict-free.
// 16 consecutive steps per thread (4 chunks), affine (U,S) composition,
// wave shfl tree reduce, cross-wave combine in-block, direct output write.
// No workspace, single dispatch.
__global__ void __launch_bounds__(TPB) onenet_fused(
    const float* __restrict__ X,   const float* __restrict__ SC,
    const float* __restrict__ pW1, const float* __restrict__ pb1,
    const float* __restrict__ pW2, const float* __restrict__ pb2,
    const float* __restrict__ rW1, const float* __restrict__ rb1,
    const float* __restrict__ rW2, const float* __restrict__ rb2,
    float* __restrict__ out)
{
    __shared__ float4 tile[5120];            // exactly 80 KB -> 2 blocks/CU

    const int row  = blockIdx.x;
    const int tid  = threadIdx.x;
    const int lane = tid & 63;
    const int w    = tid >> 6;

    const float* Xrow = X + (size_t)row * NL * 5;

    // ---- async staging: LDS dest linear per wave, source pre-swizzled ----
#pragma unroll
    for (int k = 0; k < 20; ++k) {
        int jbase = 256 * k + 64 * w;        // wave-uniform dest float4 idx
        int j     = jbase + lane;
        int sj    = j ^ ((j >> 3) & 7);      // involution: tile[sw(i)] = g[i]
        __builtin_amdgcn_global_load_lds(
            (const __attribute__((address_space(1))) void*)(Xrow + 4 * (size_t)sj),
            (__attribute__((address_space(3))) void*)&tile[jbase],
            16, 0, 0);
    }

    // ---- uniform weight prep (scalar work, overlaps the DMA) ----
    const float sc0 = SC[row * 3 + 0];
    const float sc1 = SC[row * 3 + 1];
    const float sc2 = SC[row * 3 + 2];

    float W1S[10], W1T[10], BASE[10];
    float VR1[10], VRC[10], VOC[10], VMH[10], VKH[10];
#pragma unroll
    for (int j = 0; j < 10; ++j) {
        W1S[j]  = L2E * pW1[j];
        W1T[j]  = L2E * pW1[10 + j];
        BASE[j] = L2E * fmaf(sc0, pW1[20 + j],
                        fmaf(sc1, pW1[30 + j],
                        fmaf(sc2, pW1[40 + j], pb1[j])));
    }
    const float UBLB0 = 0.015f, UBLB1 = 0.045f, UBLB2 = 0.9f,
                UBLB3 = 0.055f, UBLB4 = 0.023f;
    const float KC = LN2 * 0.0025f;
#pragma unroll
    for (int j = 0; j < 10; ++j) {
        VR1[j] = KC * UBLB0 * pW2[5 * j + 0];
        VRC[j] = KC * UBLB1 * pW2[5 * j + 1];
        VOC[j] = KC * UBLB2 * pW2[5 * j + 2];
        VMH[j] = KC * UBLB3 * pW2[5 * j + 3];
        VKH[j] = KC * UBLB4 * pW2[5 * j + 4];
    }
    const float A0 = 0.005f + UBLB0 * fmaf(0.0025f, pb2[0], 0.5f);
    const float A1 = 0.025f + UBLB1 * fmaf(0.0025f, pb2[1], 0.5f);
    const float A2 = 0.1f   + UBLB2 * fmaf(0.0025f, pb2[2], 0.5f);
    const float A3 = 0.0f   + UBLB3 * fmaf(0.0025f, pb2[3], 0.5f);
    const float A4 = 0.002f + UBLB4 * fmaf(0.0025f, pb2[4], 0.5f);

    // r-net (one-off, exact transcendentals) -> Rs, uniform per row
    float Rs;
    {
        float T0 = Xrow[2], SOC0 = Xrow[4];
        float u = rb1[0];
        u = fmaf(SOC0, rW1[0], u);
        u = fmaf(T0,   rW1[1], u);
        u = fmaf(sc0,  rW1[2], u);
        u = fmaf(sc1,  rW1[3], u);
        u = fmaf(sc2,  rW1[4], u);
        float sp = LN2 * flog2(1.0f + fexp2(L2E * u));
        Rs = sc2 * (1.0f + fmaf(sp, rW2[0], rb2[0]));
    }

    __syncthreads();                         // DMA drained (vmcnt before barrier)

    v2f a = {1.f, 1.f}, b = {0.f, 0.f}, cS = {0.f, 0.f}, dS = {0.f, 0.f};
    v2f oaccv = {0.f, 0.f};
    float OCV0 = 0.f, I0 = 0.f;
    const float* tf = (const float*)tile;

#pragma unroll
    for (int c = 0; c < NCH; ++c) {
        // this thread's chunk: steps 16*tid + 4c .. +3  (20 floats)
        float f[20];
#pragma unroll
        for (int jj = 0; jj < 5; ++jj) {
            int i4 = 20 * tid + 5 * c + jj;
            int s4 = i4 ^ ((i4 >> 3) & 7);
            *(float4*)&f[4 * jj] = tile[s4];
        }
        // t of the step after this chunk's last
        float tn;
        {
            int i4 = 20 * tid + 5 * c + 5;
            if (i4 < 5120) {
                int s4 = i4 ^ ((i4 >> 3) & 7);
                tn = tf[4 * s4];
            } else {
                tn = f[15];                  // global step 4095: dt=0 identity
            }
        }

#pragma unroll
        for (int ip = 0; ip < 2; ++ip) {     // two step-pairs per chunk
            const int i0 = 2 * ip, i1 = 2 * ip + 1;
            v2f SSv = { f[5 * i0 + 4], f[5 * i1 + 4] };
            v2f Ttv = { f[5 * i0 + 2], f[5 * i1 + 2] };
            v2f Iv  = { f[5 * i0 + 1], f[5 * i1 + 1] };
            float tnx1 = (ip == 0) ? f[5 * i1 + 5] : tn;
            v2f dtv = { f[5 * i1 + 0] - f[5 * i0 + 0], tnx1 - f[5 * i1 + 0] };
            v2f invv = { fast_rcp(Iv.x), fast_rcp(Iv.y) };

            v2f tR1 = {A0, A0}, tRC = {A1, A1}, tOC = {A2, A2},
                tMH = {A3, A3}, tKH = {A4, A4};
#pragma unroll
            for (int j = 0; j < 10; ++j) {
                v2f pre = SSv * W1S[j] + Ttv * W1T[j] + BASE[j];
                v2f s   = pre * pre;
                v2f p   = s * SP_C3 + SP_C2;
                p = s * p + SP_C1;
                p = s * p + SP_C0;
                v2f lam = pre * 0.5f + p;    // softplus2(pre), poly approx
                tR1 += lam * VR1[j];
                tRC += lam * VRC[j];
                tOC += lam * VOC[j];
                tMH += lam * VMH[j];
                tKH += lam * VKH[j];
            }
            oaccv += tOC * invv;             // negated at the end
            if (c == 0 && ip == 0) { OCV0 = tOC.x; I0 = Iv.x; }

            v2f g  = dtv * tKH * Iv;
            v2f hh = dtv * tRC;
            v2f bx = g * tMH;
            v2f by = hh * tR1 * Iv;

            {   // step i0 (S-accum with pre-step U, then apply T)
                v2f sv = {1.f + g.x, 1.f - hh.x};
                v2f bv = {bx.x, by.x};
                v2f iv = {invv.x, invv.x};
                cS = iv * a + cS;
                dS = iv * b + dS;
                b  = sv * b + bv;
                a  = sv * a;
            }
            {   // step i1
                v2f sv = {1.f + g.y, 1.f - hh.y};
                v2f bv = {bx.y, by.y};
                v2f iv = {invv.y, invv.y};
                cS = iv * a + cS;
                dS = iv * b + dS;
                b  = sv * b + bv;
                a  = sv * a;
            }
        }
    }
    float oacc = -(oaccv.x + oaccv.y);

    // wave-level order-preserving tree reduce (L=self, R=lane+off)
#pragma unroll
    for (int off = 1; off < 64; off <<= 1) {
        v2f a2, b2, c2, d2;
        a2.x = __shfl_down(a.x, off);  a2.y = __shfl_down(a.y, off);
        b2.x = __shfl_down(b.x, off);  b2.y = __shfl_down(b.y, off);
        c2.x = __shfl_down(cS.x, off); c2.y = __shfl_down(cS.y, off);
        d2.x = __shfl_down(dS.x, off); d2.y = __shfl_down(dS.y, off);
        float o2 = __shfl_down(oacc, off);
        v2f nb = a2 * b + b2;
        v2f nc = c2 * a + cS;
        v2f nd = (dS + d2) + c2 * b;
        a = a2 * a; b = nb; cS = nc; dS = nd;
        oacc += o2;
    }

    // cross-wave combine via reused tile memory (all tile reads are done)
    __syncthreads();
    float* redf = (float*)tile;
    if (lane == 0) {
        redf[w * 12 + 0] = a.x;  redf[w * 12 + 1] = a.y;
        redf[w * 12 + 2] = b.x;  redf[w * 12 + 3] = b.y;
        redf[w * 12 + 4] = cS.x; redf[w * 12 + 5] = cS.y;
        redf[w * 12 + 6] = dS.x; redf[w * 12 + 7] = dS.y;
        redf[w * 12 + 8] = oacc;
    }
    __syncthreads();

    if (tid == 0) {
#pragma unroll
        for (int k = 1; k < TPB / 64; ++k) {
            v2f ak, bk, ck, dk;
            ak.x = redf[k * 12 + 0]; ak.y = redf[k * 12 + 1];
            bk.x = redf[k * 12 + 2]; bk.y = redf[k * 12 + 3];
            ck.x = redf[k * 12 + 4]; ck.y = redf[k * 12 + 5];
            dk.x = redf[k * 12 + 6]; dk.y = redf[k * 12 + 7];
            v2f nb = ak * b + bk;
            v2f nc = ck * a + cS;
            v2f nd = (dS + dk) + ck * b;
            a = ak * a; b = nb; cS = nc; dS = nd;
            oacc += redf[k * 12 + 8];
        }
        float U10 = -OCV0 - I0 * Rs;         // U_H0 = 0
        float SH  = dS.x;                    // sum U_H/I
        float S1  = fmaf(cS.y, U10, dS.y);   // sum U_1/I
        out[row] = (oacc - SH - S1) * (1.0f / 4096.0f);
    }
}

extern "C" void kernel_launch(void* const* d_in, const int* in_sizes, int n_in,
                              void* d_out, int out_size, void* d_ws, size_t ws_size,
                              hipStream_t stream) {
    const float* X   = (const float*)d_in[0];
    const float* SC  = (const float*)d_in[1];
    const float* pW1 = (const float*)d_in[2];
    const float* pb1 = (const float*)d_in[3];
    const float* pW2 = (const float*)d_in[4];
    const float* pb2 = (const float*)d_in[5];
    const float* rW1 = (const float*)d_in[6];
    const float* rb1 = (const float*)d_in[7];
    const float* rW2 = (const float*)d_in[8];
    const float* rb2 = (const float*)d_in[9];
    float* out = (float*)d_out;
    (void)d_ws; (void)ws_size;

    onenet_fused<<<NB, TPB, 0, stream>>>(X, SC, pW1, pb1, pW2, pb2,
                                         rW1, rb1, rW2, rb2, out);
}